// Round 2
// baseline (507.477 us; speedup 1.0000x reference)
//
#include <hip/hip_runtime.h>
#include <hip/hip_bf16.h>
#include <stdint.h>

// Problem dims
#define Bn  8
#define Ln  4096
#define DHn 1024
#define Tn  1024
#define DGn 768
#define Pn  256

typedef float  f32x4  __attribute__((ext_vector_type(4)));
typedef __bf16 bf16x8 __attribute__((ext_vector_type(8)));

__device__ __forceinline__ void gload16(const void* g, void* l) {
  __builtin_amdgcn_global_load_lds(
      (const __attribute__((address_space(1))) void*)g,
      (__attribute__((address_space(3))) void*)l, 16, 0, 0);
}

__device__ __forceinline__ unsigned short f2bf(float x) {
  union { float f; uint32_t u; } v; v.f = x;
  uint32_t u = v.u;
  return (unsigned short)((u + 0x7FFFu + ((u >> 16) & 1u)) >> 16);
}

__device__ __forceinline__ float bf2f(unsigned short b) {
  union { uint32_t u; float f; } v; v.u = ((uint32_t)b) << 16;
  return v.f;
}

// ---------------- fp32 -> bf16 convert (vectorized) ----------------
__global__ void cvt_kernel(const float4* __restrict__ in,
                           ushort4* __restrict__ out, int n4) {
  int i = blockIdx.x * 256 + threadIdx.x;
  if (i < n4) {
    float4 v = in[i];
    ushort4 o;
    o.x = f2bf(v.x); o.y = f2bf(v.y); o.z = f2bf(v.z); o.w = f2bf(v.w);
    out[i] = o;
  }
}

// ------- H [B,L,DH] fp32 -> Hb [B,L,DH] bf16 AND HT [B,DH,L] bf16, one read -------
__global__ void prep_H(const float* __restrict__ Hg,
                       unsigned short* __restrict__ Hb,
                       unsigned short* __restrict__ HT) {
  __shared__ unsigned short tile[64 * 65];
  const int b  = blockIdx.z;
  const int l0 = blockIdx.x * 64;
  const int d0 = blockIdx.y * 64;
  const float4* src  = (const float4*)(Hg + (size_t)b * Ln * DHn);
  ushort4*      dstH = (ushort4*)(Hb + (size_t)b * Ln * DHn);
  for (int e = threadIdx.x; e < 1024; e += 256) {
    int l  = e >> 4;
    int d4 = e & 15;
    size_t idx4 = ((size_t)(l0 + l) * DHn + d0) / 4 + d4;
    float4 v = src[idx4];
    ushort4 o;
    o.x = f2bf(v.x); o.y = f2bf(v.y); o.z = f2bf(v.z); o.w = f2bf(v.w);
    dstH[idx4] = o;  // straight bf16 copy
    int d = d4 * 4;
    tile[(d + 0) * 65 + l] = o.x;
    tile[(d + 1) * 65 + l] = o.y;
    tile[(d + 2) * 65 + l] = o.z;
    tile[(d + 3) * 65 + l] = o.w;
  }
  __syncthreads();
  ushort4* dst = (ushort4*)(HT + (size_t)b * DHn * Ln);
  for (int e = threadIdx.x; e < 1024; e += 256) {
    int d  = e >> 4;
    int l4 = (e & 15) * 4;
    ushort4 o;
    o.x = tile[d * 65 + l4 + 0];
    o.y = tile[d * 65 + l4 + 1];
    o.z = tile[d * 65 + l4 + 2];
    o.w = tile[d * 65 + l4 + 3];
    dst[((size_t)(d0 + d) * Ln + l0) / 4 + (e & 15)] = o;
  }
}

// ---------------- bt-GEMM: C[m,n] = sum_k A[m,k]*B[n,k], 128x128 tile ----------------
// Flat grid, batch-on-XCD swizzle: b = x&7, then n-tile innermost, k-split outermost.
// EPI 0: C bf16 = acc
// EPI 1: C bf16 = exp(acc*scale), row-sums atomically added into S
// EPI 2: C fp32 = acc / (S[row] + 1e-8)
// EPI 3: C fp32 atomicAdd acc / (S[row] + 1e-8)   (split-K partials; out pre-zeroed)
template <int EPI>
__global__ __launch_bounds__(256) void gemm_bt(
    const unsigned short* __restrict__ A, const unsigned short* __restrict__ B,
    void* __restrict__ Cout, float* __restrict__ S,
    int kLen, int lda, int ldb, int ldc,
    long sA, long sB, long sC, int sS, float scale, int mTiles, int nTiles) {
  __shared__ unsigned short As[128 * 32];
  __shared__ unsigned short Bs[128 * 32];
  int x = blockIdx.x;
  const int b = x & (Bn - 1);
  int r = x >> 3;
  const int ni = r % nTiles; r /= nTiles;
  const int mi = r % mTiles;
  const int ks = r / mTiles;
  const unsigned short* Ab = A + (long)b * sA;
  const unsigned short* Bb = B + (long)b * sB;
  const int m0 = mi * 128;
  const int n0 = ni * 128;
  const int kBeg = ks * kLen;
  const int tid  = threadIdx.x;
  const int lane = tid & 63;
  const int wave = tid >> 6;
  const int wm = (wave >> 1) << 6;   // wave's 64x64 subtile
  const int wn = (wave & 1) << 6;
  const int lrow = lane & 15;
  const int quad = lane >> 4;
  const int srow0 = lane >> 2;       // staging: row within 16-row chunk
  const int skcol = (lane & 3) << 3; // staging: k offset (x8 bf16 = 16B)

  f32x4 acc[4][4];
#pragma unroll
  for (int mt = 0; mt < 4; ++mt)
#pragma unroll
    for (int nt = 0; nt < 4; ++nt) acc[mt][nt] = f32x4{0.f, 0.f, 0.f, 0.f};

  for (int k0 = kBeg; k0 < kBeg + kLen; k0 += 32) {
    __syncthreads();
#pragma unroll
    for (int j = 0; j < 2; ++j) {
      int c = wave * 2 + j;          // 8 chunks of 16 rows
      int row = c * 16 + srow0;
      gload16(Ab + (size_t)(m0 + row) * lda + (k0 + skcol), &As[c * 512]);
      gload16(Bb + (size_t)(n0 + row) * ldb + (k0 + skcol), &Bs[c * 512]);
    }
    __syncthreads();
    bf16x8 af[4], bfr[4];
#pragma unroll
    for (int mt = 0; mt < 4; ++mt)
      af[mt] = *(const bf16x8*)&As[(wm + mt * 16 + lrow) * 32 + quad * 8];
#pragma unroll
    for (int nt = 0; nt < 4; ++nt)
      bfr[nt] = *(const bf16x8*)&Bs[(wn + nt * 16 + lrow) * 32 + quad * 8];
#pragma unroll
    for (int mt = 0; mt < 4; ++mt)
#pragma unroll
      for (int nt = 0; nt < 4; ++nt)
        acc[mt][nt] = __builtin_amdgcn_mfma_f32_16x16x32_bf16(
            af[mt], bfr[nt], acc[mt][nt], 0, 0, 0);
  }

  // C/D layout (verified m89/m91): col = lane&15, row = quad*4 + reg
  if (EPI == 0) {
    unsigned short* C = (unsigned short*)Cout + (long)b * sC;
#pragma unroll
    for (int mt = 0; mt < 4; ++mt)
#pragma unroll
      for (int r2 = 0; r2 < 4; ++r2) {
        int row = m0 + wm + mt * 16 + quad * 4 + r2;
        unsigned short* Cr = C + (size_t)row * ldc + n0 + wn + lrow;
#pragma unroll
        for (int nt = 0; nt < 4; ++nt) Cr[nt * 16] = f2bf(acc[mt][nt][r2]);
      }
  } else if (EPI == 1) {
    unsigned short* C = (unsigned short*)Cout + (long)b * sC;
    float* Sb = S + (long)b * sS;
#pragma unroll
    for (int mt = 0; mt < 4; ++mt)
#pragma unroll
      for (int r2 = 0; r2 < 4; ++r2) {
        int row = m0 + wm + mt * 16 + quad * 4 + r2;
        unsigned short* Cr = C + (size_t)row * ldc + n0 + wn + lrow;
        float psum = 0.f;
#pragma unroll
        for (int nt = 0; nt < 4; ++nt) {
          float e = __expf(acc[mt][nt][r2] * scale);
          unsigned short bv = f2bf(e);
          Cr[nt * 16] = bv;
          psum += bf2f(bv);  // sum the value we actually stored
        }
        psum += __shfl_xor(psum, 1);
        psum += __shfl_xor(psum, 2);
        psum += __shfl_xor(psum, 4);
        psum += __shfl_xor(psum, 8);
        if (lrow == 0) atomicAdd(&Sb[row], psum);
      }
  } else {
    float* C = (float*)Cout + (long)b * sC;
    const float* Sb = S + (long)b * sS;
#pragma unroll
    for (int mt = 0; mt < 4; ++mt)
#pragma unroll
      for (int r2 = 0; r2 < 4; ++r2) {
        int row = m0 + wm + mt * 16 + quad * 4 + r2;
        float inv = 1.f / (Sb[row] + 1e-8f);
        float* Cr = C + (size_t)row * ldc + n0 + wn + lrow;
#pragma unroll
        for (int nt = 0; nt < 4; ++nt) {
          if (EPI == 2) Cr[nt * 16] = acc[mt][nt][r2] * inv;
          else          atomicAdd(&Cr[nt * 16], acc[mt][nt][r2] * inv);
        }
      }
  }
}

extern "C" void kernel_launch(void* const* d_in, const int* in_sizes, int n_in,
                              void* d_out, int out_size, void* d_ws, size_t ws_size,
                              hipStream_t stream) {
  const float* H  = (const float*)d_in[0];
  const float* G  = (const float*)d_in[1];
  const float* Wq = (const float*)d_in[2];
  const float* Wk = (const float*)d_in[3];
  float* out = (float*)d_out;

  char* ws = (char*)d_ws;
  size_t off = 0;
  auto alloc = [&](size_t bytes) {
    void* p = ws + off;
    off = (off + bytes + 255) & ~(size_t)255;
    return p;
  };
  unsigned short* Hb  = (unsigned short*)alloc((size_t)Bn * Ln * DHn * 2); // 64MB
  unsigned short* HbT = (unsigned short*)alloc((size_t)Bn * DHn * Ln * 2); // 64MB
  unsigned short* Gb  = (unsigned short*)alloc((size_t)Bn * Tn * DGn * 2); // 12MB
  unsigned short* Wqb = (unsigned short*)alloc((size_t)Pn * DGn * 2);
  unsigned short* Wkb = (unsigned short*)alloc((size_t)Pn * DHn * 2);
  unsigned short* Kb  = (unsigned short*)alloc((size_t)Bn * Ln * Pn * 2);  // 16MB
  unsigned short* Qb  = (unsigned short*)alloc((size_t)Bn * Tn * Pn * 2);  // 4MB
  float* Sv           = (float*)alloc((size_t)Bn * Tn * 4);                // 32KB
  // P [B,T,L] bf16 (64MB) aliases Hb: Hb is dead after K-proj, and same-stream
  // kernels serialize, so QK's writes can't race K-proj's reads.
  unsigned short* Pm = Hb;

  // 1) small converts
  {
    int n4 = Bn * Tn * DGn / 4;
    cvt_kernel<<<(n4 + 255) / 256, 256, 0, stream>>>((const float4*)G, (ushort4*)Gb, n4);
  }
  {
    int n4 = Pn * DGn / 4;
    cvt_kernel<<<(n4 + 255) / 256, 256, 0, stream>>>((const float4*)Wq, (ushort4*)Wqb, n4);
  }
  {
    int n4 = Pn * DHn / 4;
    cvt_kernel<<<(n4 + 255) / 256, 256, 0, stream>>>((const float4*)Wk, (ushort4*)Wkb, n4);
  }
  // 2) fused H convert + transpose (reads H fp32 exactly once)
  prep_H<<<dim3(Ln / 64, DHn / 64, Bn), 256, 0, stream>>>(H, Hb, HbT);
  // 3) zero softmax sums + output (PV accumulates atomically, split-K)
  hipMemsetAsync(Sv, 0, (size_t)Bn * Tn * 4, stream);
  hipMemsetAsync(out, 0, (size_t)Bn * Tn * DHn * 4, stream);

  // 4) K = H Wk^T : [L,P] per batch  (mTiles=32, nTiles=2)
  gemm_bt<0><<<Bn * 32 * 2, 256, 0, stream>>>(
      Hb, Wkb, Kb, nullptr, DHn, DHn, DHn, Pn,
      (long)Ln * DHn, 0L, (long)Ln * Pn, 0, 1.f, 32, 2);
  // 5) Q = G Wq^T : [T,P] per batch  (mTiles=8, nTiles=2)
  gemm_bt<0><<<Bn * 8 * 2, 256, 0, stream>>>(
      Gb, Wqb, Qb, nullptr, DGn, DGn, DGn, Pn,
      (long)Tn * DGn, 0L, (long)Tn * Pn, 0, 1.f, 8, 2);
  // 6) P = exp(scale * Q K^T) : [T,L] per batch, + row sums into Sv (mT=8, nT=32)
  gemm_bt<1><<<Bn * 8 * 32, 256, 0, stream>>>(
      Qb, Kb, Pm, Sv, Pn, Pn, Pn, Ln,
      (long)Tn * Pn, (long)Ln * Pn, (long)Tn * Ln, Tn, 0.0625f, 8, 32);
  // 7) Z = (P H) / (s + eps) : [T,DH] per batch, split-K x2 atomic fp32 out
  //    (mTiles=8, nTiles=8, kSplit=2 -> 1024 blocks, 4/CU)
  gemm_bt<3><<<Bn * 8 * 8 * 2, 256, 0, stream>>>(
      Pm, HbT, out, Sv, Ln / 2, Ln, Ln, DHn,
      (long)Tn * Ln, (long)DHn * Ln, (long)Tn * DHn, Tn, 1.f, 8, 8);
}

// Round 3
// 474.640 us; speedup vs baseline: 1.0692x; 1.0692x over previous
//
#include <hip/hip_runtime.h>
#include <hip/hip_bf16.h>
#include <stdint.h>

// Problem dims
#define Bn  8
#define Ln  4096
#define DHn 1024
#define Tn  1024
#define DGn 768
#define Pn  256

typedef float  f32x4  __attribute__((ext_vector_type(4)));
typedef __bf16 bf16x8 __attribute__((ext_vector_type(8)));

__device__ __forceinline__ void gload16(const void* g, void* l) {
  __builtin_amdgcn_global_load_lds(
      (const __attribute__((address_space(1))) void*)g,
      (__attribute__((address_space(3))) void*)l, 16, 0, 0);
}

__device__ __forceinline__ unsigned short f2bf(float x) {
  union { float f; uint32_t u; } v; v.f = x;
  uint32_t u = v.u;
  return (unsigned short)((u + 0x7FFFu + ((u >> 16) & 1u)) >> 16);
}

__device__ __forceinline__ float bf2f(unsigned short b) {
  union { uint32_t u; float f; } v; v.u = ((uint32_t)b) << 16;
  return v.f;
}

// ---------------- fp32 -> bf16 convert (vectorized) ----------------
__global__ void cvt_kernel(const float4* __restrict__ in,
                           ushort4* __restrict__ out, int n4) {
  int i = blockIdx.x * 256 + threadIdx.x;
  if (i < n4) {
    float4 v = in[i];
    ushort4 o;
    o.x = f2bf(v.x); o.y = f2bf(v.y); o.z = f2bf(v.z); o.w = f2bf(v.w);
    out[i] = o;
  }
}

// ------- H [B,L,DH] fp32 -> Hb [B,L,DH] bf16 AND HT [B,DH,L] bf16, one read -------
__global__ void prep_H(const float* __restrict__ Hg,
                       unsigned short* __restrict__ Hb,
                       unsigned short* __restrict__ HT) {
  __shared__ unsigned short tile[64 * 65];
  const int b  = blockIdx.z;
  const int l0 = blockIdx.x * 64;
  const int d0 = blockIdx.y * 64;
  const float4* src  = (const float4*)(Hg + (size_t)b * Ln * DHn);
  ushort4*      dstH = (ushort4*)(Hb + (size_t)b * Ln * DHn);
  for (int e = threadIdx.x; e < 1024; e += 256) {
    int l  = e >> 4;
    int d4 = e & 15;
    size_t idx4 = ((size_t)(l0 + l) * DHn + d0) / 4 + d4;
    float4 v = src[idx4];
    ushort4 o;
    o.x = f2bf(v.x); o.y = f2bf(v.y); o.z = f2bf(v.z); o.w = f2bf(v.w);
    dstH[idx4] = o;  // straight bf16 copy
    int d = d4 * 4;
    tile[(d + 0) * 65 + l] = o.x;
    tile[(d + 1) * 65 + l] = o.y;
    tile[(d + 2) * 65 + l] = o.z;
    tile[(d + 3) * 65 + l] = o.w;
  }
  __syncthreads();
  ushort4* dst = (ushort4*)(HT + (size_t)b * DHn * Ln);
  for (int e = threadIdx.x; e < 1024; e += 256) {
    int d  = e >> 4;
    int l4 = (e & 15) * 4;
    ushort4 o;
    o.x = tile[d * 65 + l4 + 0];
    o.y = tile[d * 65 + l4 + 1];
    o.z = tile[d * 65 + l4 + 2];
    o.w = tile[d * 65 + l4 + 3];
    dst[((size_t)(d0 + d) * Ln + l0) / 4 + (e & 15)] = o;
  }
}

// ---------------- bt-GEMM: C[m,n] = sum_k A[m,k]*B[n,k], 128x128 tile ----------------
// Flat grid, batch-on-XCD swizzle: b = x&7, then n-tile innermost, k-split outermost.
// Staging uses a global-side XOR swizzle (kgroup ^= (row>>1)&3) so the MFMA
// fragment ds_read_b128s land 2 lanes/bank (free) instead of 8-way conflicts.
// EPI 0: C bf16 = acc
// EPI 1: C bf16 = exp(acc*scale), row-sums atomically added into S
// EPI 2: C fp32 = acc / (S[row] + 1e-8)
// EPI 3: C fp32 = acc (split-K partial; ks==0 -> Cout, ks==1 -> CoutB)
template <int EPI>
__global__ __launch_bounds__(256) void gemm_bt(
    const unsigned short* __restrict__ A, const unsigned short* __restrict__ B,
    void* __restrict__ Cout, void* __restrict__ CoutB, float* __restrict__ S,
    int kLen, int lda, int ldb, int ldc,
    long sA, long sB, long sC, int sS, float scale, int mTiles, int nTiles) {
  __shared__ unsigned short As[128 * 32];
  __shared__ unsigned short Bs[128 * 32];
  int x = blockIdx.x;
  const int b = x & (Bn - 1);
  int r = x >> 3;
  const int ni = r % nTiles; r /= nTiles;
  const int mi = r % mTiles;
  const int ks = r / mTiles;
  const unsigned short* Ab = A + (long)b * sA;
  const unsigned short* Bb = B + (long)b * sB;
  const int m0 = mi * 128;
  const int n0 = ni * 128;
  const int kBeg = ks * kLen;
  const int tid  = threadIdx.x;
  const int lane = tid & 63;
  const int wave = tid >> 6;
  const int wm = (wave >> 1) << 6;   // wave's 64x64 subtile
  const int wn = (wave & 1) << 6;
  const int lrow = lane & 15;
  const int quad = lane >> 4;
  const int srow0 = lane >> 2;       // staging: row within 16-row chunk
  // global-side XOR swizzle: this lane stages k-group (lane&3)^((srow0>>1)&3)
  const int skcol = (((lane & 3) ^ ((srow0 >> 1) & 3)) << 3);
  // fragment read un-swizzle: slot = quad ^ ((lrow>>1)&3)
  const int fslot = (quad ^ ((lrow >> 1) & 3)) << 3;

  f32x4 acc[4][4];
#pragma unroll
  for (int mt = 0; mt < 4; ++mt)
#pragma unroll
    for (int nt = 0; nt < 4; ++nt) acc[mt][nt] = f32x4{0.f, 0.f, 0.f, 0.f};

  for (int k0 = kBeg; k0 < kBeg + kLen; k0 += 32) {
    __syncthreads();
#pragma unroll
    for (int j = 0; j < 2; ++j) {
      int c = wave * 2 + j;          // 8 chunks of 16 rows
      int row = c * 16 + srow0;
      gload16(Ab + (size_t)(m0 + row) * lda + (k0 + skcol), &As[c * 512]);
      gload16(Bb + (size_t)(n0 + row) * ldb + (k0 + skcol), &Bs[c * 512]);
    }
    __syncthreads();
    bf16x8 af[4], bfr[4];
#pragma unroll
    for (int mt = 0; mt < 4; ++mt)
      af[mt] = *(const bf16x8*)&As[(wm + mt * 16 + lrow) * 32 + fslot];
#pragma unroll
    for (int nt = 0; nt < 4; ++nt)
      bfr[nt] = *(const bf16x8*)&Bs[(wn + nt * 16 + lrow) * 32 + fslot];
#pragma unroll
    for (int mt = 0; mt < 4; ++mt)
#pragma unroll
      for (int nt = 0; nt < 4; ++nt)
        acc[mt][nt] = __builtin_amdgcn_mfma_f32_16x16x32_bf16(
            af[mt], bfr[nt], acc[mt][nt], 0, 0, 0);
  }

  // C/D layout (verified m89/m91): col = lane&15, row = quad*4 + reg
  if (EPI == 0) {
    unsigned short* C = (unsigned short*)Cout + (long)b * sC;
#pragma unroll
    for (int mt = 0; mt < 4; ++mt)
#pragma unroll
      for (int r2 = 0; r2 < 4; ++r2) {
        int row = m0 + wm + mt * 16 + quad * 4 + r2;
        unsigned short* Cr = C + (size_t)row * ldc + n0 + wn + lrow;
#pragma unroll
        for (int nt = 0; nt < 4; ++nt) Cr[nt * 16] = f2bf(acc[mt][nt][r2]);
      }
  } else if (EPI == 1) {
    unsigned short* C = (unsigned short*)Cout + (long)b * sC;
    float* Sb = S + (long)b * sS;
#pragma unroll
    for (int mt = 0; mt < 4; ++mt)
#pragma unroll
      for (int r2 = 0; r2 < 4; ++r2) {
        int row = m0 + wm + mt * 16 + quad * 4 + r2;
        unsigned short* Cr = C + (size_t)row * ldc + n0 + wn + lrow;
        float psum = 0.f;
#pragma unroll
        for (int nt = 0; nt < 4; ++nt) {
          float e = __expf(acc[mt][nt][r2] * scale);
          unsigned short bv = f2bf(e);
          Cr[nt * 16] = bv;
          psum += bf2f(bv);  // sum the value we actually stored
        }
        psum += __shfl_xor(psum, 1);
        psum += __shfl_xor(psum, 2);
        psum += __shfl_xor(psum, 4);
        psum += __shfl_xor(psum, 8);
        if (lrow == 0) atomicAdd(&Sb[row], psum);
      }
  } else if (EPI == 2) {
    float* C = (float*)Cout + (long)b * sC;
    const float* Sb = S + (long)b * sS;
#pragma unroll
    for (int mt = 0; mt < 4; ++mt)
#pragma unroll
      for (int r2 = 0; r2 < 4; ++r2) {
        int row = m0 + wm + mt * 16 + quad * 4 + r2;
        float inv = 1.f / (Sb[row] + 1e-8f);
        float* Cr = C + (size_t)row * ldc + n0 + wn + lrow;
#pragma unroll
        for (int nt = 0; nt < 4; ++nt) Cr[nt * 16] = acc[mt][nt][r2] * inv;
      }
  } else {
    // split-K partial, plain fp32 store
    float* C = (float*)(ks == 0 ? Cout : CoutB) + (long)b * sC;
#pragma unroll
    for (int mt = 0; mt < 4; ++mt)
#pragma unroll
      for (int r2 = 0; r2 < 4; ++r2) {
        int row = m0 + wm + mt * 16 + quad * 4 + r2;
        float* Cr = C + (size_t)row * ldc + n0 + wn + lrow;
#pragma unroll
        for (int nt = 0; nt < 4; ++nt) Cr[nt * 16] = acc[mt][nt][r2];
      }
  }
}

// ---- out = (out + part1) / (S[row] + eps), row = global T-row of element ----
__global__ void reduce_norm(float4* __restrict__ out,
                            const float4* __restrict__ p1,
                            const float* __restrict__ S, int n4) {
  int i = blockIdx.x * 256 + threadIdx.x;
  if (i < n4) {
    int row = i >> 8;  // DHn/4 = 256 float4 per row; rows flat over [B*T]
    float inv = 1.f / (S[row] + 1e-8f);
    float4 a = out[i];
    float4 c = p1[i];
    float4 o;
    o.x = (a.x + c.x) * inv;
    o.y = (a.y + c.y) * inv;
    o.z = (a.z + c.z) * inv;
    o.w = (a.w + c.w) * inv;
    out[i] = o;
  }
}

extern "C" void kernel_launch(void* const* d_in, const int* in_sizes, int n_in,
                              void* d_out, int out_size, void* d_ws, size_t ws_size,
                              hipStream_t stream) {
  const float* H  = (const float*)d_in[0];
  const float* G  = (const float*)d_in[1];
  const float* Wq = (const float*)d_in[2];
  const float* Wk = (const float*)d_in[3];
  float* out = (float*)d_out;

  char* ws = (char*)d_ws;
  size_t off = 0;
  auto alloc = [&](size_t bytes) {
    void* p = ws + off;
    off = (off + bytes + 255) & ~(size_t)255;
    return p;
  };
  unsigned short* Hb  = (unsigned short*)alloc((size_t)Bn * Ln * DHn * 2); // 64MB
  unsigned short* HbT = (unsigned short*)alloc((size_t)Bn * DHn * Ln * 2); // 64MB
  unsigned short* Gb  = (unsigned short*)alloc((size_t)Bn * Tn * DGn * 2); // 12MB
  unsigned short* Wqb = (unsigned short*)alloc((size_t)Pn * DGn * 2);
  unsigned short* Wkb = (unsigned short*)alloc((size_t)Pn * DHn * 2);
  unsigned short* Kb  = (unsigned short*)alloc((size_t)Bn * Ln * Pn * 2);  // 16MB
  unsigned short* Qb  = (unsigned short*)alloc((size_t)Bn * Tn * Pn * 2);  // 4MB
  float* Sv           = (float*)alloc((size_t)Bn * Tn * 4);                // 32KB
  // P [B,T,L] bf16 (64MB) aliases Hb: Hb is dead after K-proj.
  unsigned short* Pm = Hb;
  // Split-K partial 1 (32MB fp32) aliases the Gb..Qb span (all dead after the
  // QK dispatch; span is 34.5MB >= 33.55MB needed and ends before Sv).
  float* Part1 = (float*)Gb;

  // 1) small converts
  {
    int n4 = Bn * Tn * DGn / 4;
    cvt_kernel<<<(n4 + 255) / 256, 256, 0, stream>>>((const float4*)G, (ushort4*)Gb, n4);
  }
  {
    int n4 = Pn * DGn / 4;
    cvt_kernel<<<(n4 + 255) / 256, 256, 0, stream>>>((const float4*)Wq, (ushort4*)Wqb, n4);
  }
  {
    int n4 = Pn * DHn / 4;
    cvt_kernel<<<(n4 + 255) / 256, 256, 0, stream>>>((const float4*)Wk, (ushort4*)Wkb, n4);
  }
  // 2) fused H convert + transpose (reads H fp32 exactly once)
  prep_H<<<dim3(Ln / 64, DHn / 64, Bn), 256, 0, stream>>>(H, Hb, HbT);
  // 3) zero softmax sums
  hipMemsetAsync(Sv, 0, (size_t)Bn * Tn * 4, stream);

  // 4) K = H Wk^T : [L,P] per batch  (mTiles=32, nTiles=2)
  gemm_bt<0><<<Bn * 32 * 2, 256, 0, stream>>>(
      Hb, Wkb, Kb, nullptr, nullptr, DHn, DHn, DHn, Pn,
      (long)Ln * DHn, 0L, (long)Ln * Pn, 0, 1.f, 32, 2);
  // 5) Q = G Wq^T : [T,P] per batch  (mTiles=8, nTiles=2)
  gemm_bt<0><<<Bn * 8 * 2, 256, 0, stream>>>(
      Gb, Wqb, Qb, nullptr, nullptr, DGn, DGn, DGn, Pn,
      (long)Tn * DGn, 0L, (long)Tn * Pn, 0, 1.f, 8, 2);
  // 6) P = exp(scale * Q K^T) : [T,L] per batch, + row sums into Sv (mT=8, nT=32)
  gemm_bt<1><<<Bn * 8 * 32, 256, 0, stream>>>(
      Qb, Kb, Pm, nullptr, Sv, Pn, Pn, Pn, Ln,
      (long)Tn * Pn, (long)Ln * Pn, (long)Tn * Ln, Tn, 0.0625f, 8, 32);
  // 7) Z-partials = P H : split-K x2, plain fp32 stores (ks0 -> out, ks1 -> Part1)
  gemm_bt<3><<<Bn * 8 * 8 * 2, 256, 0, stream>>>(
      Pm, HbT, out, Part1, nullptr, Ln / 2, Ln, Ln, DHn,
      (long)Tn * Ln, (long)DHn * Ln, (long)Tn * DHn, 0, 1.f, 8, 8);
  // 8) out = (out + Part1) / (Sv + eps)
  {
    int n4 = Bn * Tn * DHn / 4;
    reduce_norm<<<(n4 + 255) / 256, 256, 0, stream>>>(
        (float4*)out, (const float4*)Part1, Sv, n4);
  }
}

// Round 4
// 470.343 us; speedup vs baseline: 1.0790x; 1.0091x over previous
//
#include <hip/hip_runtime.h>
#include <hip/hip_bf16.h>
#include <stdint.h>

// Problem dims
#define Bn  8
#define Ln  4096
#define DHn 1024
#define Tn  1024
#define DGn 768
#define Pn  256

typedef float  f32x4  __attribute__((ext_vector_type(4)));
typedef __bf16 bf16x8 __attribute__((ext_vector_type(8)));

__device__ __forceinline__ void gload16(const void* g, void* l) {
  __builtin_amdgcn_global_load_lds(
      (const __attribute__((address_space(1))) void*)g,
      (__attribute__((address_space(3))) void*)l, 16, 0, 0);
}

__device__ __forceinline__ unsigned short f2bf(float x) {
  union { float f; uint32_t u; } v; v.f = x;
  uint32_t u = v.u;
  return (unsigned short)((u + 0x7FFFu + ((u >> 16) & 1u)) >> 16);
}

__device__ __forceinline__ float bf2f(unsigned short b) {
  union { uint32_t u; float f; } v; v.u = ((uint32_t)b) << 16;
  return v.f;
}

// ---------------- fp32 -> bf16 convert (vectorized) ----------------
__global__ void cvt_kernel(const float4* __restrict__ in,
                           ushort4* __restrict__ out, int n4) {
  int i = blockIdx.x * 256 + threadIdx.x;
  if (i < n4) {
    float4 v = in[i];
    ushort4 o;
    o.x = f2bf(v.x); o.y = f2bf(v.y); o.z = f2bf(v.z); o.w = f2bf(v.w);
    out[i] = o;
  }
}

// ------- H [B,L,DH] fp32 -> Hb [B,L,DH] bf16 AND HT [B,DH,L] bf16, one read -------
__global__ void prep_H(const float* __restrict__ Hg,
                       unsigned short* __restrict__ Hb,
                       unsigned short* __restrict__ HT) {
  __shared__ unsigned short tile[64 * 65];
  const int b  = blockIdx.z;
  const int l0 = blockIdx.x * 64;
  const int d0 = blockIdx.y * 64;
  const float4* src  = (const float4*)(Hg + (size_t)b * Ln * DHn);
  ushort4*      dstH = (ushort4*)(Hb + (size_t)b * Ln * DHn);
  for (int e = threadIdx.x; e < 1024; e += 256) {
    int l  = e >> 4;
    int d4 = e & 15;
    size_t idx4 = ((size_t)(l0 + l) * DHn + d0) / 4 + d4;
    float4 v = src[idx4];
    ushort4 o;
    o.x = f2bf(v.x); o.y = f2bf(v.y); o.z = f2bf(v.z); o.w = f2bf(v.w);
    dstH[idx4] = o;  // straight bf16 copy
    int d = d4 * 4;
    tile[(d + 0) * 65 + l] = o.x;
    tile[(d + 1) * 65 + l] = o.y;
    tile[(d + 2) * 65 + l] = o.z;
    tile[(d + 3) * 65 + l] = o.w;
  }
  __syncthreads();
  ushort4* dst = (ushort4*)(HT + (size_t)b * DHn * Ln);
  for (int e = threadIdx.x; e < 1024; e += 256) {
    int d  = e >> 4;
    int l4 = (e & 15) * 4;
    ushort4 o;
    o.x = tile[d * 65 + l4 + 0];
    o.y = tile[d * 65 + l4 + 1];
    o.z = tile[d * 65 + l4 + 2];
    o.w = tile[d * 65 + l4 + 3];
    dst[((size_t)(d0 + d) * Ln + l0) / 4 + (e & 15)] = o;
  }
}

// ---------------- bt-GEMM: C[m,n] = sum_k A[m,k]*B[n,k], 128x128 tile ----------------
// Flat grid, batch-on-XCD swizzle: b = x&7, then n-tile innermost.
// Staging uses a global-side XOR swizzle (kgroup ^= (row>>1)&3) so the MFMA
// fragment ds_read_b128s land 2 lanes/bank (free, m136) instead of 8-way
// conflicts. Verified R3: SQ_LDS_BANK_CONFLICT 8.4M -> 0.
// EPI 0: C bf16 = acc
// EPI 1: C bf16 = exp(acc*scale), row-sums atomically added into S
// EPI 2: C fp32 = acc / (S[row] + 1e-8)
template <int EPI>
__global__ __launch_bounds__(256) void gemm_bt(
    const unsigned short* __restrict__ A, const unsigned short* __restrict__ B,
    void* __restrict__ Cout, float* __restrict__ S,
    int kLen, int lda, int ldb, int ldc,
    long sA, long sB, long sC, int sS, float scale, int mTiles, int nTiles) {
  __shared__ unsigned short As[128 * 32];
  __shared__ unsigned short Bs[128 * 32];
  int x = blockIdx.x;
  const int b = x & (Bn - 1);
  int r = x >> 3;
  const int ni = r % nTiles; r /= nTiles;
  const int mi = r;
  const unsigned short* Ab = A + (long)b * sA;
  const unsigned short* Bb = B + (long)b * sB;
  const int m0 = mi * 128;
  const int n0 = ni * 128;
  const int tid  = threadIdx.x;
  const int lane = tid & 63;
  const int wave = tid >> 6;
  const int wm = (wave >> 1) << 6;   // wave's 64x64 subtile
  const int wn = (wave & 1) << 6;
  const int lrow = lane & 15;
  const int quad = lane >> 4;
  const int srow0 = lane >> 2;       // staging: row within 16-row chunk
  // global-side XOR swizzle: this lane stages k-group (lane&3)^((srow0>>1)&3)
  const int skcol = (((lane & 3) ^ ((srow0 >> 1) & 3)) << 3);
  // fragment read un-swizzle: slot = quad ^ ((lrow>>1)&3)
  const int fslot = (quad ^ ((lrow >> 1) & 3)) << 3;

  f32x4 acc[4][4];
#pragma unroll
  for (int mt = 0; mt < 4; ++mt)
#pragma unroll
    for (int nt = 0; nt < 4; ++nt) acc[mt][nt] = f32x4{0.f, 0.f, 0.f, 0.f};

  for (int k0 = 0; k0 < kLen; k0 += 32) {
    __syncthreads();
#pragma unroll
    for (int j = 0; j < 2; ++j) {
      int c = wave * 2 + j;          // 8 chunks of 16 rows
      int row = c * 16 + srow0;
      gload16(Ab + (size_t)(m0 + row) * lda + (k0 + skcol), &As[c * 512]);
      gload16(Bb + (size_t)(n0 + row) * ldb + (k0 + skcol), &Bs[c * 512]);
    }
    __syncthreads();
    bf16x8 af[4], bfr[4];
#pragma unroll
    for (int mt = 0; mt < 4; ++mt)
      af[mt] = *(const bf16x8*)&As[(wm + mt * 16 + lrow) * 32 + fslot];
#pragma unroll
    for (int nt = 0; nt < 4; ++nt)
      bfr[nt] = *(const bf16x8*)&Bs[(wn + nt * 16 + lrow) * 32 + fslot];
#pragma unroll
    for (int mt = 0; mt < 4; ++mt)
#pragma unroll
      for (int nt = 0; nt < 4; ++nt)
        acc[mt][nt] = __builtin_amdgcn_mfma_f32_16x16x32_bf16(
            af[mt], bfr[nt], acc[mt][nt], 0, 0, 0);
  }

  // C/D layout (verified m89/m91): col = lane&15, row = quad*4 + reg
  if (EPI == 0) {
    unsigned short* C = (unsigned short*)Cout + (long)b * sC;
#pragma unroll
    for (int mt = 0; mt < 4; ++mt)
#pragma unroll
      for (int r2 = 0; r2 < 4; ++r2) {
        int row = m0 + wm + mt * 16 + quad * 4 + r2;
        unsigned short* Cr = C + (size_t)row * ldc + n0 + wn + lrow;
#pragma unroll
        for (int nt = 0; nt < 4; ++nt) Cr[nt * 16] = f2bf(acc[mt][nt][r2]);
      }
  } else if (EPI == 1) {
    unsigned short* C = (unsigned short*)Cout + (long)b * sC;
    float* Sb = S + (long)b * sS;
#pragma unroll
    for (int mt = 0; mt < 4; ++mt)
#pragma unroll
      for (int r2 = 0; r2 < 4; ++r2) {
        int row = m0 + wm + mt * 16 + quad * 4 + r2;
        unsigned short* Cr = C + (size_t)row * ldc + n0 + wn + lrow;
        float psum = 0.f;
#pragma unroll
        for (int nt = 0; nt < 4; ++nt) {
          float e = __expf(acc[mt][nt][r2] * scale);
          unsigned short bv = f2bf(e);
          Cr[nt * 16] = bv;
          psum += bf2f(bv);  // sum the value we actually stored
        }
        psum += __shfl_xor(psum, 1);
        psum += __shfl_xor(psum, 2);
        psum += __shfl_xor(psum, 4);
        psum += __shfl_xor(psum, 8);
        if (lrow == 0) atomicAdd(&Sb[row], psum);
      }
  } else {
    float* C = (float*)Cout + (long)b * sC;
    const float* Sb = S + (long)b * sS;
#pragma unroll
    for (int mt = 0; mt < 4; ++mt)
#pragma unroll
      for (int r2 = 0; r2 < 4; ++r2) {
        int row = m0 + wm + mt * 16 + quad * 4 + r2;
        float inv = 1.f / (Sb[row] + 1e-8f);
        float* Cr = C + (size_t)row * ldc + n0 + wn + lrow;
#pragma unroll
        for (int nt = 0; nt < 4; ++nt) Cr[nt * 16] = acc[mt][nt][r2] * inv;
      }
  }
}

extern "C" void kernel_launch(void* const* d_in, const int* in_sizes, int n_in,
                              void* d_out, int out_size, void* d_ws, size_t ws_size,
                              hipStream_t stream) {
  const float* H  = (const float*)d_in[0];
  const float* G  = (const float*)d_in[1];
  const float* Wq = (const float*)d_in[2];
  const float* Wk = (const float*)d_in[3];
  float* out = (float*)d_out;

  char* ws = (char*)d_ws;
  size_t off = 0;
  auto alloc = [&](size_t bytes) {
    void* p = ws + off;
    off = (off + bytes + 255) & ~(size_t)255;
    return p;
  };
  unsigned short* Hb  = (unsigned short*)alloc((size_t)Bn * Ln * DHn * 2); // 64MB
  unsigned short* HbT = (unsigned short*)alloc((size_t)Bn * DHn * Ln * 2); // 64MB
  unsigned short* Gb  = (unsigned short*)alloc((size_t)Bn * Tn * DGn * 2); // 12MB
  unsigned short* Wqb = (unsigned short*)alloc((size_t)Pn * DGn * 2);
  unsigned short* Wkb = (unsigned short*)alloc((size_t)Pn * DHn * 2);
  unsigned short* Kb  = (unsigned short*)alloc((size_t)Bn * Ln * Pn * 2);  // 16MB
  unsigned short* Qb  = (unsigned short*)alloc((size_t)Bn * Tn * Pn * 2);  // 4MB
  float* Sv           = (float*)alloc((size_t)Bn * Tn * 4);                // 32KB
  // P [B,T,L] bf16 (64MB) aliases Hb: Hb is dead after K-proj, and same-stream
  // kernels serialize, so QK's writes can't race K-proj's reads.
  unsigned short* Pm = Hb;

  // 1) small converts
  {
    int n4 = Bn * Tn * DGn / 4;
    cvt_kernel<<<(n4 + 255) / 256, 256, 0, stream>>>((const float4*)G, (ushort4*)Gb, n4);
  }
  {
    int n4 = Pn * DGn / 4;
    cvt_kernel<<<(n4 + 255) / 256, 256, 0, stream>>>((const float4*)Wq, (ushort4*)Wqb, n4);
  }
  {
    int n4 = Pn * DHn / 4;
    cvt_kernel<<<(n4 + 255) / 256, 256, 0, stream>>>((const float4*)Wk, (ushort4*)Wkb, n4);
  }
  // 2) fused H convert + transpose (reads H fp32 exactly once)
  prep_H<<<dim3(Ln / 64, DHn / 64, Bn), 256, 0, stream>>>(H, Hb, HbT);
  // 3) zero softmax sums
  hipMemsetAsync(Sv, 0, (size_t)Bn * Tn * 4, stream);

  // 4) K = H Wk^T : [L,P] per batch  (mTiles=32, nTiles=2)
  gemm_bt<0><<<Bn * 32 * 2, 256, 0, stream>>>(
      Hb, Wkb, Kb, nullptr, DHn, DHn, DHn, Pn,
      (long)Ln * DHn, 0L, (long)Ln * Pn, 0, 1.f, 32, 2);
  // 5) Q = G Wq^T : [T,P] per batch  (mTiles=8, nTiles=2)
  gemm_bt<0><<<Bn * 8 * 2, 256, 0, stream>>>(
      Gb, Wqb, Qb, nullptr, DGn, DGn, DGn, Pn,
      (long)Tn * DGn, 0L, (long)Tn * Pn, 0, 1.f, 8, 2);
  // 6) P = exp(scale * Q K^T) : [T,L] per batch, + row sums into Sv (mT=8, nT=32)
  gemm_bt<1><<<Bn * 8 * 32, 256, 0, stream>>>(
      Qb, Kb, Pm, Sv, Pn, Pn, Pn, Ln,
      (long)Tn * Pn, (long)Ln * Pn, (long)Tn * Ln, Tn, 0.0625f, 8, 32);
  // 7) Z = (P H) / (s + eps) : full-K, fp32 out, normalize in epilogue (mT=8, nT=8)
  gemm_bt<2><<<Bn * 8 * 8, 256, 0, stream>>>(
      Pm, HbT, out, Sv, Ln, Ln, Ln, DHn,
      (long)Tn * Ln, (long)DHn * Ln, (long)Tn * DHn, Tn, 1.f, 8, 8);
}

// Round 5
// 454.688 us; speedup vs baseline: 1.1161x; 1.0344x over previous
//
#include <hip/hip_runtime.h>
#include <hip/hip_bf16.h>
#include <stdint.h>

// Problem dims
#define Bn  8
#define Ln  4096
#define DHn 1024
#define Tn  1024
#define DGn 768
#define Pn  256

typedef float  f32x4  __attribute__((ext_vector_type(4)));
typedef __bf16 bf16x8 __attribute__((ext_vector_type(8)));

__device__ __forceinline__ void gload16(const void* g, void* l) {
  __builtin_amdgcn_global_load_lds(
      (const __attribute__((address_space(1))) void*)g,
      (__attribute__((address_space(3))) void*)l, 16, 0, 0);
}

__device__ __forceinline__ unsigned short f2bf(float x) {
  union { float f; uint32_t u; } v; v.f = x;
  uint32_t u = v.u;
  return (unsigned short)((u + 0x7FFFu + ((u >> 16) & 1u)) >> 16);
}

__device__ __forceinline__ float bf2f(unsigned short b) {
  union { uint32_t u; float f; } v; v.u = ((uint32_t)b) << 16;
  return v.f;
}

// ---------------- fp32 -> bf16 convert (vectorized) ----------------
__global__ void cvt_kernel(const float4* __restrict__ in,
                           ushort4* __restrict__ out, int n4) {
  int i = blockIdx.x * 256 + threadIdx.x;
  if (i < n4) {
    float4 v = in[i];
    ushort4 o;
    o.x = f2bf(v.x); o.y = f2bf(v.y); o.z = f2bf(v.z); o.w = f2bf(v.w);
    out[i] = o;
  }
}

// ------- H [B,L,DH] fp32 -> Hb [B,L,DH] bf16 AND HT [B,DH,L] bf16, one read -------
__global__ void prep_H(const float* __restrict__ Hg,
                       unsigned short* __restrict__ Hb,
                       unsigned short* __restrict__ HT) {
  __shared__ unsigned short tile[64 * 65];
  const int b  = blockIdx.z;
  const int l0 = blockIdx.x * 64;
  const int d0 = blockIdx.y * 64;
  const float4* src  = (const float4*)(Hg + (size_t)b * Ln * DHn);
  ushort4*      dstH = (ushort4*)(Hb + (size_t)b * Ln * DHn);
  for (int e = threadIdx.x; e < 1024; e += 256) {
    int l  = e >> 4;
    int d4 = e & 15;
    size_t idx4 = ((size_t)(l0 + l) * DHn + d0) / 4 + d4;
    float4 v = src[idx4];
    ushort4 o;
    o.x = f2bf(v.x); o.y = f2bf(v.y); o.z = f2bf(v.z); o.w = f2bf(v.w);
    dstH[idx4] = o;  // straight bf16 copy
    int d = d4 * 4;
    tile[(d + 0) * 65 + l] = o.x;
    tile[(d + 1) * 65 + l] = o.y;
    tile[(d + 2) * 65 + l] = o.z;
    tile[(d + 3) * 65 + l] = o.w;
  }
  __syncthreads();
  ushort4* dst = (ushort4*)(HT + (size_t)b * DHn * Ln);
  for (int e = threadIdx.x; e < 1024; e += 256) {
    int d  = e >> 4;
    int l4 = (e & 15) * 4;
    ushort4 o;
    o.x = tile[d * 65 + l4 + 0];
    o.y = tile[d * 65 + l4 + 1];
    o.z = tile[d * 65 + l4 + 2];
    o.w = tile[d * 65 + l4 + 3];
    dst[((size_t)(d0 + d) * Ln + l0) / 4 + (e & 15)] = o;
  }
}

// ------------- bt-GEMM: C[m,n] = sum_k A[m,k]*B[n,k], 128 x (NT*32) tile -------------
// Flat grid, batch-on-XCD swizzle: b = x&7, then n-tile innermost.
// NT = wave n-subtiles: NT=4 -> 128x128 block tile, NT=2 -> 128x64 (doubles grid
// for occupancy-limited shapes; R4 measured 2 blk/CU -> 4 blk/CU = -9% dur).
// Staging uses a global-side XOR swizzle (kgroup ^= (row>>1)&3) so the MFMA
// fragment ds_read_b128s land 2 lanes/bank (free, m136). Verified R3: conflicts 8.4M -> 0.
// EPI 0: C bf16 = acc
// EPI 1: C bf16 = exp(acc*scale), row-sums atomically added into S
// EPI 2: C fp32 = acc / (S[row] + 1e-8)
template <int EPI, int NT>
__global__ __launch_bounds__(256) void gemm_bt(
    const unsigned short* __restrict__ A, const unsigned short* __restrict__ B,
    void* __restrict__ Cout, float* __restrict__ S,
    int kLen, int lda, int ldb, int ldc,
    long sA, long sB, long sC, int sS, float scale, int nTiles) {
  constexpr int Nn = NT * 32;          // block n-extent
  __shared__ unsigned short As[128 * 32];
  __shared__ unsigned short Bs[Nn * 32];
  int x = blockIdx.x;
  const int b = x & (Bn - 1);
  int r = x >> 3;
  const int ni = r % nTiles;
  const int mi = r / nTiles;
  const unsigned short* Ab = A + (long)b * sA;
  const unsigned short* Bb = B + (long)b * sB;
  const int m0 = mi * 128;
  const int n0 = ni * Nn;
  const int tid  = threadIdx.x;
  const int lane = tid & 63;
  const int wave = tid >> 6;
  const int wm = (wave >> 1) << 6;        // wave m-offset (2 waves over 128 rows)
  const int wn = (wave & 1) * (NT * 16);  // wave n-offset (2 waves over Nn cols)
  const int lrow = lane & 15;
  const int quad = lane >> 4;
  const int srow0 = lane >> 2;       // staging: row within 16-row chunk
  // global-side XOR swizzle: this lane stages k-group (lane&3)^((srow0>>1)&3)
  const int skcol = (((lane & 3) ^ ((srow0 >> 1) & 3)) << 3);
  // fragment read un-swizzle: slot = quad ^ ((lrow>>1)&3)
  const int fslot = (quad ^ ((lrow >> 1) & 3)) << 3;

  f32x4 acc[4][NT];
#pragma unroll
  for (int mt = 0; mt < 4; ++mt)
#pragma unroll
    for (int nt = 0; nt < NT; ++nt) acc[mt][nt] = f32x4{0.f, 0.f, 0.f, 0.f};

  constexpr int NBC = NT / 2;  // B staging chunks (16 rows each) per wave
  for (int k0 = 0; k0 < kLen; k0 += 32) {
    __syncthreads();
#pragma unroll
    for (int j = 0; j < 2; ++j) {
      int c = wave * 2 + j;          // A: 8 chunks of 16 rows
      int row = c * 16 + srow0;
      gload16(Ab + (size_t)(m0 + row) * lda + (k0 + skcol), &As[c * 512]);
    }
#pragma unroll
    for (int j = 0; j < NBC; ++j) {
      int c = wave * NBC + j;        // B: Nn/16 chunks of 16 rows
      int row = c * 16 + srow0;
      gload16(Bb + (size_t)(n0 + row) * ldb + (k0 + skcol), &Bs[c * 512]);
    }
    __syncthreads();
    bf16x8 af[4], bfr[NT];
#pragma unroll
    for (int mt = 0; mt < 4; ++mt)
      af[mt] = *(const bf16x8*)&As[(wm + mt * 16 + lrow) * 32 + fslot];
#pragma unroll
    for (int nt = 0; nt < NT; ++nt)
      bfr[nt] = *(const bf16x8*)&Bs[(wn + nt * 16 + lrow) * 32 + fslot];
#pragma unroll
    for (int mt = 0; mt < 4; ++mt)
#pragma unroll
      for (int nt = 0; nt < NT; ++nt)
        acc[mt][nt] = __builtin_amdgcn_mfma_f32_16x16x32_bf16(
            af[mt], bfr[nt], acc[mt][nt], 0, 0, 0);
  }

  // C/D layout (verified m89/m91): col = lane&15, row = quad*4 + reg
  if (EPI == 0) {
    unsigned short* C = (unsigned short*)Cout + (long)b * sC;
#pragma unroll
    for (int mt = 0; mt < 4; ++mt)
#pragma unroll
      for (int r2 = 0; r2 < 4; ++r2) {
        int row = m0 + wm + mt * 16 + quad * 4 + r2;
        unsigned short* Cr = C + (size_t)row * ldc + n0 + wn + lrow;
#pragma unroll
        for (int nt = 0; nt < NT; ++nt) Cr[nt * 16] = f2bf(acc[mt][nt][r2]);
      }
  } else if (EPI == 1) {
    unsigned short* C = (unsigned short*)Cout + (long)b * sC;
    float* Sb = S + (long)b * sS;
#pragma unroll
    for (int mt = 0; mt < 4; ++mt)
#pragma unroll
      for (int r2 = 0; r2 < 4; ++r2) {
        int row = m0 + wm + mt * 16 + quad * 4 + r2;
        unsigned short* Cr = C + (size_t)row * ldc + n0 + wn + lrow;
        float psum = 0.f;
#pragma unroll
        for (int nt = 0; nt < NT; ++nt) {
          float e = __expf(acc[mt][nt][r2] * scale);
          unsigned short bv = f2bf(e);
          Cr[nt * 16] = bv;
          psum += bf2f(bv);  // sum the value we actually stored
        }
        psum += __shfl_xor(psum, 1);
        psum += __shfl_xor(psum, 2);
        psum += __shfl_xor(psum, 4);
        psum += __shfl_xor(psum, 8);
        if (lrow == 0) atomicAdd(&Sb[row], psum);
      }
  } else {
    float* C = (float*)Cout + (long)b * sC;
    const float* Sb = S + (long)b * sS;
#pragma unroll
    for (int mt = 0; mt < 4; ++mt)
#pragma unroll
      for (int r2 = 0; r2 < 4; ++r2) {
        int row = m0 + wm + mt * 16 + quad * 4 + r2;
        float inv = 1.f / (Sb[row] + 1e-8f);
        float* Cr = C + (size_t)row * ldc + n0 + wn + lrow;
#pragma unroll
        for (int nt = 0; nt < NT; ++nt) Cr[nt * 16] = acc[mt][nt][r2] * inv;
      }
  }
}

extern "C" void kernel_launch(void* const* d_in, const int* in_sizes, int n_in,
                              void* d_out, int out_size, void* d_ws, size_t ws_size,
                              hipStream_t stream) {
  const float* H  = (const float*)d_in[0];
  const float* G  = (const float*)d_in[1];
  const float* Wq = (const float*)d_in[2];
  const float* Wk = (const float*)d_in[3];
  float* out = (float*)d_out;

  char* ws = (char*)d_ws;
  size_t off = 0;
  auto alloc = [&](size_t bytes) {
    void* p = ws + off;
    off = (off + bytes + 255) & ~(size_t)255;
    return p;
  };
  unsigned short* Hb  = (unsigned short*)alloc((size_t)Bn * Ln * DHn * 2); // 64MB
  unsigned short* HbT = (unsigned short*)alloc((size_t)Bn * DHn * Ln * 2); // 64MB
  unsigned short* Gb  = (unsigned short*)alloc((size_t)Bn * Tn * DGn * 2); // 12MB
  unsigned short* Wqb = (unsigned short*)alloc((size_t)Pn * DGn * 2);
  unsigned short* Wkb = (unsigned short*)alloc((size_t)Pn * DHn * 2);
  unsigned short* Kb  = (unsigned short*)alloc((size_t)Bn * Ln * Pn * 2);  // 16MB
  unsigned short* Qb  = (unsigned short*)alloc((size_t)Bn * Tn * Pn * 2);  // 4MB
  float* Sv           = (float*)alloc((size_t)Bn * Tn * 4);                // 32KB
  // P [B,T,L] bf16 (64MB) aliases Hb: Hb is dead after K-proj, and same-stream
  // kernels serialize, so QK's writes can't race K-proj's reads.
  unsigned short* Pm = Hb;

  // 1) small converts
  {
    int n4 = Bn * Tn * DGn / 4;
    cvt_kernel<<<(n4 + 255) / 256, 256, 0, stream>>>((const float4*)G, (ushort4*)Gb, n4);
  }
  {
    int n4 = Pn * DGn / 4;
    cvt_kernel<<<(n4 + 255) / 256, 256, 0, stream>>>((const float4*)Wq, (ushort4*)Wqb, n4);
  }
  {
    int n4 = Pn * DHn / 4;
    cvt_kernel<<<(n4 + 255) / 256, 256, 0, stream>>>((const float4*)Wk, (ushort4*)Wkb, n4);
  }
  // 2) fused H convert + transpose (reads H fp32 exactly once)
  prep_H<<<dim3(Ln / 64, DHn / 64, Bn), 256, 0, stream>>>(H, Hb, HbT);
  // 3) zero softmax sums
  hipMemsetAsync(Sv, 0, (size_t)Bn * Tn * 4, stream);

  // 4) K = H Wk^T : [L,P] per batch, 128x64 tiles (32 m x 4 n x 8 b = 1024 blocks)
  gemm_bt<0, 2><<<Bn * 32 * 4, 256, 0, stream>>>(
      Hb, Wkb, Kb, nullptr, DHn, DHn, DHn, Pn,
      (long)Ln * DHn, 0L, (long)Ln * Pn, 0, 1.f, 4);
  // 5) Q = G Wq^T : [T,P] per batch, 128x64 tiles (8 x 4 x 8 = 256 blocks)
  gemm_bt<0, 2><<<Bn * 8 * 4, 256, 0, stream>>>(
      Gb, Wqb, Qb, nullptr, DGn, DGn, DGn, Pn,
      (long)Tn * DGn, 0L, (long)Tn * Pn, 0, 1.f, 4);
  // 6) P = exp(scale * Q K^T) : [T,L], 128x128 tiles (8 x 32 x 8 = 2048 blocks)
  gemm_bt<1, 4><<<Bn * 8 * 32, 256, 0, stream>>>(
      Qb, Kb, Pm, Sv, Pn, Pn, Pn, Ln,
      (long)Tn * Pn, (long)Ln * Pn, (long)Tn * Ln, Tn, 0.0625f, 32);
  // 7) Z = (P H) / (s + eps) : [T,DH], 128x64 tiles (8 x 16 x 8 = 1024 blocks)
  gemm_bt<2, 2><<<Bn * 8 * 16, 256, 0, stream>>>(
      Pm, HbT, out, Sv, Ln, Ln, Ln, DHn,
      (long)Tn * Ln, (long)DHn * Ln, (long)Tn * DHn, Tn, 1.f, 16);
}

// Round 6
// 431.655 us; speedup vs baseline: 1.1757x; 1.0534x over previous
//
#include <hip/hip_runtime.h>
#include <hip/hip_bf16.h>
#include <stdint.h>

// Problem dims
#define Bn  8
#define Ln  4096
#define DHn 1024
#define Tn  1024
#define DGn 768
#define Pn  256

typedef float  f32x4  __attribute__((ext_vector_type(4)));
typedef __bf16 bf16x8 __attribute__((ext_vector_type(8)));

__device__ __forceinline__ void gload16(const void* g, void* l) {
  __builtin_amdgcn_global_load_lds(
      (const __attribute__((address_space(1))) void*)g,
      (__attribute__((address_space(3))) void*)l, 16, 0, 0);
}

__device__ __forceinline__ unsigned short f2bf(float x) {
  union { float f; uint32_t u; } v; v.f = x;
  uint32_t u = v.u;
  return (unsigned short)((u + 0x7FFFu + ((u >> 16) & 1u)) >> 16);
}

__device__ __forceinline__ float bf2f(unsigned short b) {
  union { uint32_t u; float f; } v; v.u = ((uint32_t)b) << 16;
  return v.f;
}

// ---------------- fp32 -> bf16 convert (vectorized) ----------------
__global__ void cvt_kernel(const float4* __restrict__ in,
                           ushort4* __restrict__ out, int n4) {
  int i = blockIdx.x * 256 + threadIdx.x;
  if (i < n4) {
    float4 v = in[i];
    ushort4 o;
    o.x = f2bf(v.x); o.y = f2bf(v.y); o.z = f2bf(v.z); o.w = f2bf(v.w);
    out[i] = o;
  }
}

// ------- H [B,L,DH] fp32 -> Hb [B,L,DH] bf16 AND HT [B,DH,L] bf16, one read -------
__global__ void prep_H(const float* __restrict__ Hg,
                       unsigned short* __restrict__ Hb,
                       unsigned short* __restrict__ HT) {
  __shared__ unsigned short tile[64 * 65];
  const int b  = blockIdx.z;
  const int l0 = blockIdx.x * 64;
  const int d0 = blockIdx.y * 64;
  const float4* src  = (const float4*)(Hg + (size_t)b * Ln * DHn);
  ushort4*      dstH = (ushort4*)(Hb + (size_t)b * Ln * DHn);
  for (int e = threadIdx.x; e < 1024; e += 256) {
    int l  = e >> 4;
    int d4 = e & 15;
    size_t idx4 = ((size_t)(l0 + l) * DHn + d0) / 4 + d4;
    float4 v = src[idx4];
    ushort4 o;
    o.x = f2bf(v.x); o.y = f2bf(v.y); o.z = f2bf(v.z); o.w = f2bf(v.w);
    dstH[idx4] = o;  // straight bf16 copy
    int d = d4 * 4;
    tile[(d + 0) * 65 + l] = o.x;
    tile[(d + 1) * 65 + l] = o.y;
    tile[(d + 2) * 65 + l] = o.z;
    tile[(d + 3) * 65 + l] = o.w;
  }
  __syncthreads();
  ushort4* dst = (ushort4*)(HT + (size_t)b * DHn * Ln);
  for (int e = threadIdx.x; e < 1024; e += 256) {
    int d  = e >> 4;
    int l4 = (e & 15) * 4;
    ushort4 o;
    o.x = tile[d * 65 + l4 + 0];
    o.y = tile[d * 65 + l4 + 1];
    o.z = tile[d * 65 + l4 + 2];
    o.w = tile[d * 65 + l4 + 3];
    dst[((size_t)(d0 + d) * Ln + l0) / 4 + (e & 15)] = o;
  }
}

// ---------- bt-GEMM: C[m,n] = sum_k A[m,k]*B[n,k], 128 x (NT*32) tile, BK k-step ----------
// Flat grid, batch-on-XCD swizzle: b = x&7, then n-tile innermost.
// BK=64 halves barrier/drain count per MFMA (R5: iter-slot was ~138cyc vs 38cyc
// of MFMA -> drain-bound). LDS stays 24KB at NT=2 so 4 blk/CU is preserved.
// Bank-conflict-free staging swizzles (R3 verified conflicts 8.4M -> 0):
//   BK=32: row stride 64B; lane stages kgroup (lane&3)^((lane>>3)&3);
//          fragment slot = quad^((lrow>>1)&3).
//   BK=64: row stride 128B (banks wrap per row); lane stages kgroup
//          (lane&7)^((lane>>3)&7); fragment slot = (h*4+quad)^(lrow&7).
// EPI 0: C bf16 = acc
// EPI 1: C bf16 = exp(acc*scale), row-sums atomically added into S
// EPI 2: C fp32 = acc / (S[row] + 1e-8)
template <int EPI, int NT, int BK>
__global__ __launch_bounds__(256) void gemm_bt(
    const unsigned short* __restrict__ A, const unsigned short* __restrict__ B,
    void* __restrict__ Cout, float* __restrict__ S,
    int kLen, int lda, int ldb, int ldc,
    long sA, long sB, long sC, int sS, float scale, int nTiles) {
  constexpr int Nn  = NT * 32;             // block n-extent
  constexpr int RPC = 1024 / (BK * 2);     // rows per 1KB staging chunk
  constexpr int APW = (128 * BK * 2 / 1024) / 4;  // A chunks per wave
  constexpr int BPW = (Nn  * BK * 2 / 1024) / 4;  // B chunks per wave
  __shared__ unsigned short As[128 * BK];
  __shared__ unsigned short Bs[Nn * BK];
  int x = blockIdx.x;
  const int b = x & (Bn - 1);
  int r = x >> 3;
  const int ni = r % nTiles;
  const int mi = r / nTiles;
  const unsigned short* Ab = A + (long)b * sA;
  const unsigned short* Bb = B + (long)b * sB;
  const int m0 = mi * 128;
  const int n0 = ni * Nn;
  const int tid  = threadIdx.x;
  const int lane = tid & 63;
  const int wave = tid >> 6;
  const int wm = (wave >> 1) << 6;        // wave m-offset (2 waves over 128 rows)
  const int wn = (wave & 1) * (NT * 16);  // wave n-offset (2 waves over Nn cols)
  const int lrow = lane & 15;
  const int quad = lane >> 4;
  // staging: row within chunk + swizzled k-offset (see header comment)
  const int srow  = (BK == 32) ? (lane >> 2) : (lane >> 3);
  const int skcol = (BK == 32)
      ? (((lane & 3) ^ ((lane >> 3) & 3)) << 3)
      : (((lane & 7) ^ ((lane >> 3) & 7)) << 3);

  f32x4 acc[4][NT];
#pragma unroll
  for (int mt = 0; mt < 4; ++mt)
#pragma unroll
    for (int nt = 0; nt < NT; ++nt) acc[mt][nt] = f32x4{0.f, 0.f, 0.f, 0.f};

  for (int k0 = 0; k0 < kLen; k0 += BK) {
    __syncthreads();
#pragma unroll
    for (int j = 0; j < APW; ++j) {
      int c = wave * APW + j;
      gload16(Ab + (size_t)(m0 + c * RPC + srow) * lda + (k0 + skcol), &As[c * 512]);
    }
#pragma unroll
    for (int j = 0; j < BPW; ++j) {
      int c = wave * BPW + j;
      gload16(Bb + (size_t)(n0 + c * RPC + srow) * ldb + (k0 + skcol), &Bs[c * 512]);
    }
    __syncthreads();
#pragma unroll
    for (int h = 0; h < BK / 32; ++h) {
      const int fsl = (BK == 32)
          ? ((quad ^ ((lrow >> 1) & 3)) << 3)
          : ((((h << 2) + quad) ^ (lrow & 7)) << 3);
      bf16x8 af[4], bfr[NT];
#pragma unroll
      for (int mt = 0; mt < 4; ++mt)
        af[mt] = *(const bf16x8*)&As[(wm + mt * 16 + lrow) * BK + fsl];
#pragma unroll
      for (int nt = 0; nt < NT; ++nt)
        bfr[nt] = *(const bf16x8*)&Bs[(wn + nt * 16 + lrow) * BK + fsl];
#pragma unroll
      for (int mt = 0; mt < 4; ++mt)
#pragma unroll
        for (int nt = 0; nt < NT; ++nt)
          acc[mt][nt] = __builtin_amdgcn_mfma_f32_16x16x32_bf16(
              af[mt], bfr[nt], acc[mt][nt], 0, 0, 0);
    }
  }

  // C/D layout (verified m89/m91): col = lane&15, row = quad*4 + reg
  if (EPI == 0) {
    unsigned short* C = (unsigned short*)Cout + (long)b * sC;
#pragma unroll
    for (int mt = 0; mt < 4; ++mt)
#pragma unroll
      for (int r2 = 0; r2 < 4; ++r2) {
        int row = m0 + wm + mt * 16 + quad * 4 + r2;
        unsigned short* Cr = C + (size_t)row * ldc + n0 + wn + lrow;
#pragma unroll
        for (int nt = 0; nt < NT; ++nt) Cr[nt * 16] = f2bf(acc[mt][nt][r2]);
      }
  } else if (EPI == 1) {
    unsigned short* C = (unsigned short*)Cout + (long)b * sC;
    float* Sb = S + (long)b * sS;
#pragma unroll
    for (int mt = 0; mt < 4; ++mt)
#pragma unroll
      for (int r2 = 0; r2 < 4; ++r2) {
        int row = m0 + wm + mt * 16 + quad * 4 + r2;
        unsigned short* Cr = C + (size_t)row * ldc + n0 + wn + lrow;
        float psum = 0.f;
#pragma unroll
        for (int nt = 0; nt < NT; ++nt) {
          float e = __expf(acc[mt][nt][r2] * scale);
          unsigned short bv = f2bf(e);
          Cr[nt * 16] = bv;
          psum += bf2f(bv);  // sum the value we actually stored
        }
        psum += __shfl_xor(psum, 1);
        psum += __shfl_xor(psum, 2);
        psum += __shfl_xor(psum, 4);
        psum += __shfl_xor(psum, 8);
        if (lrow == 0) atomicAdd(&Sb[row], psum);
      }
  } else {
    float* C = (float*)Cout + (long)b * sC;
    const float* Sb = S + (long)b * sS;
#pragma unroll
    for (int mt = 0; mt < 4; ++mt)
#pragma unroll
      for (int r2 = 0; r2 < 4; ++r2) {
        int row = m0 + wm + mt * 16 + quad * 4 + r2;
        float inv = 1.f / (Sb[row] + 1e-8f);
        float* Cr = C + (size_t)row * ldc + n0 + wn + lrow;
#pragma unroll
        for (int nt = 0; nt < NT; ++nt) Cr[nt * 16] = acc[mt][nt][r2] * inv;
      }
  }
}

extern "C" void kernel_launch(void* const* d_in, const int* in_sizes, int n_in,
                              void* d_out, int out_size, void* d_ws, size_t ws_size,
                              hipStream_t stream) {
  const float* H  = (const float*)d_in[0];
  const float* G  = (const float*)d_in[1];
  const float* Wq = (const float*)d_in[2];
  const float* Wk = (const float*)d_in[3];
  float* out = (float*)d_out;

  char* ws = (char*)d_ws;
  size_t off = 0;
  auto alloc = [&](size_t bytes) {
    void* p = ws + off;
    off = (off + bytes + 255) & ~(size_t)255;
    return p;
  };
  unsigned short* Hb  = (unsigned short*)alloc((size_t)Bn * Ln * DHn * 2); // 64MB
  unsigned short* HbT = (unsigned short*)alloc((size_t)Bn * DHn * Ln * 2); // 64MB
  unsigned short* Gb  = (unsigned short*)alloc((size_t)Bn * Tn * DGn * 2); // 12MB
  unsigned short* Wqb = (unsigned short*)alloc((size_t)Pn * DGn * 2);
  unsigned short* Wkb = (unsigned short*)alloc((size_t)Pn * DHn * 2);
  unsigned short* Kb  = (unsigned short*)alloc((size_t)Bn * Ln * Pn * 2);  // 16MB
  unsigned short* Qb  = (unsigned short*)alloc((size_t)Bn * Tn * Pn * 2);  // 4MB
  float* Sv           = (float*)alloc((size_t)Bn * Tn * 4);                // 32KB
  // P [B,T,L] bf16 (64MB) aliases Hb: Hb is dead after K-proj, and same-stream
  // kernels serialize, so QK's writes can't race K-proj's reads.
  unsigned short* Pm = Hb;

  // 1) small converts
  {
    int n4 = Bn * Tn * DGn / 4;
    cvt_kernel<<<(n4 + 255) / 256, 256, 0, stream>>>((const float4*)G, (ushort4*)Gb, n4);
  }
  {
    int n4 = Pn * DGn / 4;
    cvt_kernel<<<(n4 + 255) / 256, 256, 0, stream>>>((const float4*)Wq, (ushort4*)Wqb, n4);
  }
  {
    int n4 = Pn * DHn / 4;
    cvt_kernel<<<(n4 + 255) / 256, 256, 0, stream>>>((const float4*)Wk, (ushort4*)Wkb, n4);
  }
  // 2) fused H convert + transpose (reads H fp32 exactly once)
  prep_H<<<dim3(Ln / 64, DHn / 64, Bn), 256, 0, stream>>>(H, Hb, HbT);
  // 3) zero softmax sums
  hipMemsetAsync(Sv, 0, (size_t)Bn * Tn * 4, stream);

  // 4) K = H Wk^T : [L,P] per batch, 128x64 tiles, BK=64 (32 x 4 x 8 = 1024 blocks)
  gemm_bt<0, 2, 64><<<Bn * 32 * 4, 256, 0, stream>>>(
      Hb, Wkb, Kb, nullptr, DHn, DHn, DHn, Pn,
      (long)Ln * DHn, 0L, (long)Ln * Pn, 0, 1.f, 4);
  // 5) Q = G Wq^T : [T,P] per batch, 128x64 tiles, BK=64 (8 x 4 x 8 = 256 blocks)
  gemm_bt<0, 2, 64><<<Bn * 8 * 4, 256, 0, stream>>>(
      Gb, Wqb, Qb, nullptr, DGn, DGn, DGn, Pn,
      (long)Tn * DGn, 0L, (long)Tn * Pn, 0, 1.f, 4);
  // 6) P = exp(scale * Q K^T) : [T,L], 128x128 tiles, BK=32 (8 x 32 x 8 = 2048 blocks)
  gemm_bt<1, 4, 32><<<Bn * 8 * 32, 256, 0, stream>>>(
      Qb, Kb, Pm, Sv, Pn, Pn, Pn, Ln,
      (long)Tn * Pn, (long)Ln * Pn, (long)Tn * Ln, Tn, 0.0625f, 32);
  // 7) Z = (P H) / (s + eps) : [T,DH], 128x64 tiles, BK=64 (8 x 16 x 8 = 1024 blocks)
  gemm_bt<2, 2, 64><<<Bn * 8 * 16, 256, 0, stream>>>(
      Pm, HbT, out, Sv, Ln, Ln, Ln, DHn,
      (long)Tn * Ln, (long)DHn * Ln, (long)Tn * DHn, Tn, 1.f, 16);
}